// Round 1
// baseline (572.485 us; speedup 1.0000x reference)
//
#include <hip/hip_runtime.h>
#include <math.h>

#define BH   32
#define NH   16
#define MM   1024
#define DD   64
#define PP   1024
#define SPAN 1024
#define MT   64          // rows per block tile
#define PC   64          // p-chunk
#define TILES (MM/MT)    // 16

// Block: 256 threads. Thread map for compute: tr = t>>4 (0..15) owns rows r0=4*tr,
// tc = t&15 owns cols/dims c0=4*tc. 16-lane subgroups (same tr) share a wave.
__launch_bounds__(256)
__global__ void pm_kernel(const float* __restrict__ q,
                          const float* __restrict__ attn,
                          const float* __restrict__ key,
                          const float* __restrict__ val,
                          float* __restrict__ attn_out,
                          float* __restrict__ out)
{
    __shared__ float qs[MT][68];   // q[m][d], pad->2-way max on b128 reads
    __shared__ float ks[PC][68];   // key chunk TRANSPOSED [pc][d]
    __shared__ float vs[PC][DD];   // val chunk [pc][d]
    __shared__ float sc[MT][66];   // prob chunk [r][pc], pad 66: 4 subgroups hit banks {0,8,16,24}
    __shared__ float rmax[MT];
    __shared__ float rsum[MT];

    const int t    = threadIdx.x;
    const int bh   = blockIdx.y;
    const int tile = blockIdx.x;
    const int h    = bh & (NH - 1);
    const int m0   = tile * MT;

    const int tr   = t >> 4;
    const int tc   = t & 15;
    const int r0   = tr * 4;
    const int c0   = tc * 4;
    const int lane = t & 63;
    const int wave = t >> 6;

    const size_t qbase = (size_t)bh * MM * DD + (size_t)m0 * DD;
    const size_t abase = (size_t)bh * MM * SPAN + (size_t)m0 * SPAN;
    const size_t kbase = (size_t)h * DD * PP;
    const size_t vbase = (size_t)h * PP * DD;

    // ---- stage q tile (coalesced) ----
#pragma unroll
    for (int j = 0; j < 16; ++j) {
        int idx = j * 256 + t;
        int r = idx >> 6, d = idx & 63;
        qs[r][d] = q[qbase + (size_t)r * DD + d];
    }

    // ---- attn stats: wave w handles rows 16w..16w+15 ----
    for (int rr = 0; rr < 16; ++rr) {
        int r = wave * 16 + rr;
        const float* arow = attn + abase + (size_t)r * SPAN;
        float av[16];
        float mx = -INFINITY;
#pragma unroll
        for (int j = 0; j < 16; ++j) {
            av[j] = arow[j * 64 + lane] * 0.125f;
            mx = fmaxf(mx, av[j]);
        }
#pragma unroll
        for (int s = 32; s; s >>= 1) mx = fmaxf(mx, __shfl_xor(mx, s));
        float sm = 0.f;
#pragma unroll
        for (int j = 0; j < 16; ++j) sm += __expf(av[j] - mx);
#pragma unroll
        for (int s = 32; s; s >>= 1) sm += __shfl_xor(sm, s);
        if (lane == 0) { rmax[r] = mx; rsum[r] = sm; }
    }
    __syncthreads();

    // ---- pass A: persistent-score stats (online merge), S recomputed later ----
    for (int p0 = 0; p0 < PP; p0 += PC) {
        if (p0) __syncthreads();           // protect ks from previous chunk's readers
#pragma unroll
        for (int j = 0; j < 16; ++j) {
            int idx = j * 256 + t;
            int d = idx >> 6, pc = idx & 63;
            ks[pc][d] = key[kbase + (size_t)d * PP + p0 + pc];
        }
        __syncthreads();

        float acc[4][4] = {};
#pragma unroll
        for (int d0 = 0; d0 < DD; d0 += 4) {
            float4 q4[4], k4[4];
#pragma unroll
            for (int rr = 0; rr < 4; ++rr) q4[rr] = *(const float4*)&qs[r0 + rr][d0];
#pragma unroll
            for (int cc = 0; cc < 4; ++cc) k4[cc] = *(const float4*)&ks[c0 + cc][d0];
#pragma unroll
            for (int rr = 0; rr < 4; ++rr)
#pragma unroll
                for (int cc = 0; cc < 4; ++cc)
                    acc[rr][cc] += q4[rr].x * k4[cc].x + q4[rr].y * k4[cc].y
                                 + q4[rr].z * k4[cc].z + q4[rr].w * k4[cc].w;
        }
        // per-row chunk stats, reduced over the 16-lane subgroup, merged online
#pragma unroll
        for (int rr = 0; rr < 4; ++rr) {
            float mx = fmaxf(fmaxf(acc[rr][0], acc[rr][1]), fmaxf(acc[rr][2], acc[rr][3]));
#pragma unroll
            for (int s = 8; s; s >>= 1) mx = fmaxf(mx, __shfl_xor(mx, s));
            float sm = 0.f;
#pragma unroll
            for (int cc = 0; cc < 4; ++cc) sm += __expf(acc[rr][cc] - mx);
#pragma unroll
            for (int s = 8; s; s >>= 1) sm += __shfl_xor(sm, s);
            if (tc == 0) {
                int r = r0 + rr;
                float om = rmax[r], os = rsum[r];
                float nm = fmaxf(om, mx);
                rsum[r] = os * __expf(om - nm) + sm * __expf(mx - nm);
                rmax[r] = nm;
            }
        }
    }
    __syncthreads();    // stats final

    // ---- attn_out: re-read attn, write normalized probs ----
    for (int rr = 0; rr < 16; ++rr) {
        int r = wave * 16 + rr;
        float Mx = rmax[r];
        float iZ = 1.0f / rsum[r];
        const float* arow = attn + abase + (size_t)r * SPAN;
        float* orow = attn_out + abase + (size_t)r * SPAN;
#pragma unroll
        for (int j = 0; j < 16; ++j) {
            float a = arow[j * 64 + lane] * 0.125f;
            orow[j * 64 + lane] = __expf(a - Mx) * iZ;
        }
    }

    // ---- pass B: recompute S chunks -> probs -> PV accumulate ----
    float acc2[4][4] = {};
    for (int p0 = 0; p0 < PP; p0 += PC) {
        __syncthreads();                   // protect ks/vs/sc from previous readers
#pragma unroll
        for (int j = 0; j < 16; ++j) {
            int idx = j * 256 + t;
            int d = idx >> 6, pc = idx & 63;
            ks[pc][d] = key[kbase + (size_t)d * PP + p0 + pc];
        }
#pragma unroll
        for (int j = 0; j < 16; ++j) {
            int idx = j * 256 + t;
            int pc = idx >> 6, d = idx & 63;
            vs[pc][d] = val[vbase + (size_t)(p0 + pc) * DD + d];
        }
        __syncthreads();

        float acc[4][4] = {};
#pragma unroll
        for (int d0 = 0; d0 < DD; d0 += 4) {
            float4 q4[4], k4[4];
#pragma unroll
            for (int rr = 0; rr < 4; ++rr) q4[rr] = *(const float4*)&qs[r0 + rr][d0];
#pragma unroll
            for (int cc = 0; cc < 4; ++cc) k4[cc] = *(const float4*)&ks[c0 + cc][d0];
#pragma unroll
            for (int rr = 0; rr < 4; ++rr)
#pragma unroll
                for (int cc = 0; cc < 4; ++cc)
                    acc[rr][cc] += q4[rr].x * k4[cc].x + q4[rr].y * k4[cc].y
                                 + q4[rr].z * k4[cc].z + q4[rr].w * k4[cc].w;
        }
#pragma unroll
        for (int rr = 0; rr < 4; ++rr) {
            float Mx = rmax[r0 + rr];
#pragma unroll
            for (int cc = 0; cc < 4; ++cc)
                sc[r0 + rr][c0 + cc] = __expf(acc[rr][cc] - Mx);
        }
        __syncthreads();

        // PV: thread (tr,tc) owns rows r0..r0+3, dims 4*tc..4*tc+3
        for (int pc = 0; pc < PC; ++pc) {
            float4 v4 = *(const float4*)&vs[pc][tc * 4];
#pragma unroll
            for (int rr = 0; rr < 4; ++rr) {
                float pr = sc[r0 + rr][pc];
                acc2[rr][0] += pr * v4.x;
                acc2[rr][1] += pr * v4.y;
                acc2[rr][2] += pr * v4.z;
                acc2[rr][3] += pr * v4.w;
            }
        }
    }

    // ---- write out (×32/Z), coalesced float4 ----
#pragma unroll
    for (int rr = 0; rr < 4; ++rr) {
        int r = r0 + rr;
        float s = 32.0f / rsum[r];
        float4 o;
        o.x = acc2[rr][0] * s; o.y = acc2[rr][1] * s;
        o.z = acc2[rr][2] * s; o.w = acc2[rr][3] * s;
        *(float4*)&out[(size_t)bh * MM * DD + (size_t)(m0 + r) * DD + tc * 4] = o;
    }
}

extern "C" void kernel_launch(void* const* d_in, const int* in_sizes, int n_in,
                              void* d_out, int out_size, void* d_ws, size_t ws_size,
                              hipStream_t stream) {
    const float* q    = (const float*)d_in[0];
    const float* attn = (const float*)d_in[1];
    const float* key  = (const float*)d_in[2];
    const float* val  = (const float*)d_in[3];
    float* attn_out = (float*)d_out;
    float* out      = (float*)d_out + (size_t)BH * MM * SPAN;
    dim3 grid(TILES, BH);
    pm_kernel<<<grid, 256, 0, stream>>>(q, attn, key, val, attn_out, out);
}

// Round 2
// 124.275 us; speedup vs baseline: 4.6066x; 4.6066x over previous
//
#include <hip/hip_runtime.h>
#include <hip/hip_bf16.h>
#include <math.h>

#define BH   32
#define NH   16
#define MM   1024
#define DD   64
#define PP   1024
#define SPAN 1024

typedef unsigned short ushort_t;
typedef __attribute__((ext_vector_type(8))) short  short8;
typedef __attribute__((ext_vector_type(4))) float  f32x4;
typedef __attribute__((ext_vector_type(4))) unsigned short ushort4v;

#define MFMA(a,b,c) __builtin_amdgcn_mfma_f32_16x16x32_bf16(a,b,c,0,0,0)

// ws layout (ushort element offsets)
#define QHI_OFF 0u
#define QLO_OFF 2097152u
#define K_OFF   4194304u
#define V_OFF   6291456u
#define WS_NEED (16777216ull)   // bytes

__device__ __forceinline__ ushort_t f2bf(float x) {
    __hip_bfloat16 b = __float2bfloat16(x);
    return __builtin_bit_cast(unsigned short, b);
}
__device__ __forceinline__ float bf2f(ushort_t u) {
    __hip_bfloat16 b = __builtin_bit_cast(__hip_bfloat16, u);
    return __bfloat162float(b);
}

// ---------------- pre-kernel: split-bf16 conversion + fragment packing ----------------
// blocks [0,2048): q -> qhi/qlo (row-major)
// blocks [2048,2560): key -> K frag blobs: slot(l,e) = key[h][ks*32+(l>>4)*8+e][c*64+pb*16+(l&15)]
// blocks [2560,3072): val -> V frag blobs: slot(l,e) = val[h][c*64+ks2*32+(l>>4)*4+(e&3)+16*(e>>2)][db*16+(l&15)]
__launch_bounds__(256)
__global__ void pm_pre(const float* __restrict__ q,
                       const float* __restrict__ key,
                       const float* __restrict__ val,
                       ushort_t* __restrict__ ws)
{
    int bi = blockIdx.x, t = threadIdx.x;
    if (bi < 2048) {
        int idx = bi * 256 + t;                       // 4 floats per thread
        float4 v = ((const float4*)q)[idx];
        float f[4] = {v.x, v.y, v.z, v.w};
        ushort4v hi, lo;
#pragma unroll
        for (int e = 0; e < 4; ++e) {
            ushort_t h = f2bf(f[e]);
            hi[e] = h;
            lo[e] = f2bf(f[e] - bf2f(h));
        }
        ((ushort4v*)(ws + QHI_OFF))[idx] = hi;
        ((ushort4v*)(ws + QLO_OFF))[idx] = lo;
    } else if (bi < 2560) {
        int id = (bi - 2048) * 256 + t;               // 131072 total
        int l  = id & 63;
        int ks = (id >> 6) & 1;
        int pb = (id >> 7) & 3;
        int c  = (id >> 9) & 15;
        int h  = id >> 13;
        int p     = c * 64 + pb * 16 + (l & 15);
        int dbase = ks * 32 + (l >> 4) * 8;
        size_t fo = (size_t)(((((h * 16 + c) * 4 + pb) * 2 + ks) * 2)) * 512 + (size_t)l * 8;
        ushort_t* wsK = ws + K_OFF;
#pragma unroll
        for (int e = 0; e < 8; ++e) {
            float x = key[(size_t)(h * 64 + dbase + e) * PP + p];
            ushort_t hh = f2bf(x);
            wsK[fo + e]       = hh;
            wsK[fo + 512 + e] = f2bf(x - bf2f(hh));
        }
    } else {
        int id = (bi - 2560) * 256 + t;               // 131072 total
        int l   = id & 63;
        int db  = (id >> 6) & 3;
        int ks2 = (id >> 8) & 1;
        int c   = (id >> 9) & 15;
        int h   = id >> 13;
        int d = db * 16 + (l & 15);
        size_t fo = (size_t)(((((h * 16 + c) * 2 + ks2) * 4 + db) * 2)) * 512 + (size_t)l * 8;
        ushort_t* wsV = ws + V_OFF;
#pragma unroll
        for (int e = 0; e < 8; ++e) {
            int p = c * 64 + ks2 * 32 + ((l >> 4) * 4) + (e & 3) + 16 * (e >> 2);
            float x = val[(size_t)(h * PP + p) * DD + d];
            ushort_t hh = f2bf(x);
            wsV[fo + e]       = hh;
            wsV[fo + 512 + e] = f2bf(x - bf2f(hh));
        }
    }
}

// ---------------- main kernel: flash persistent-attention, no barriers ----------------
__launch_bounds__(256)
__global__ void pm_main(const float* __restrict__ attn,
                        const ushort_t* __restrict__ ws,
                        float* __restrict__ attn_out,
                        float* __restrict__ out)
{
    __shared__ float lds_mr[64], lds_sr[64], lds_M[64], lds_Z[64];

    const ushort_t* qhi = ws + QHI_OFF;
    const ushort_t* qlo = ws + QLO_OFF;
    const ushort_t* wsK = ws + K_OFF;
    const ushort_t* wsV = ws + V_OFF;

    const int t  = threadIdx.x;
    const int w  = t >> 6;
    const int l  = t & 63;
    const int bi = blockIdx.x;
    const int bh   = bi & 31;     // bi%8 == bh%8 -> same-h blocks share an XCD's L2
    const int tile = bi >> 5;
    const int h  = bh & (NH - 1);
    const int hi = l >> 4;
    const int lo = l & 15;
    const int m0 = tile * 64 + w * 16;

    // Q fragments (B-operand of S^T mfma): slot(l,e) = Q[m0+ (l&15)][ks*32 + (l>>4)*8 + e]
    short8 qf[2][2];
    {
        size_t qro = ((size_t)bh * MM + m0 + lo) * DD;
#pragma unroll
        for (int ks = 0; ks < 2; ++ks) {
            qf[ks][0] = *(const short8*)(qhi + qro + ks * 32 + hi * 8);
            qf[ks][1] = *(const short8*)(qlo + qro + ks * 32 + hi * 8);
        }
    }

    f32x4 oacc[4] = {{0.f,0.f,0.f,0.f},{0.f,0.f,0.f,0.f},{0.f,0.f,0.f,0.f},{0.f,0.f,0.f,0.f}};
    float m_run = -INFINITY, s_run = 0.f;

    const ushort_t* Kb = wsK + (size_t)h * 131072;
    const ushort_t* Vb = wsV + (size_t)h * 131072;

    for (int c = 0; c < 16; ++c) {
        const ushort_t* Kc = Kb + c * 8192;
        const ushort_t* Vc = Vb + c * 8192;

        // ---- S^T chunk: D[p][m], p = c*64 + pb*16 + hi*4 + reg, m = lo ----
        f32x4 sacc[4] = {{0.f,0.f,0.f,0.f},{0.f,0.f,0.f,0.f},{0.f,0.f,0.f,0.f},{0.f,0.f,0.f,0.f}};
#pragma unroll
        for (int pb = 0; pb < 4; ++pb) {
#pragma unroll
            for (int ks = 0; ks < 2; ++ks) {
                const ushort_t* fp = Kc + (pb * 2 + ks) * 1024 + l * 8;
                short8 khi = *(const short8*)fp;
                short8 klo = *(const short8*)(fp + 512);
                sacc[pb] = MFMA(khi, qf[ks][0], sacc[pb]);
                sacc[pb] = MFMA(khi, qf[ks][1], sacc[pb]);
                sacc[pb] = MFMA(klo, qf[ks][0], sacc[pb]);
            }
        }

        // ---- online softmax over the 64-p chunk (per m = lo, replicated over hi) ----
        float cm = -INFINITY;
#pragma unroll
        for (int pb = 0; pb < 4; ++pb)
#pragma unroll
            for (int r = 0; r < 4; ++r) cm = fmaxf(cm, sacc[pb][r]);
        cm = fmaxf(cm, __shfl_xor(cm, 16));
        cm = fmaxf(cm, __shfl_xor(cm, 32));
        float mnew = fmaxf(m_run, cm);

        float ep[4][4];
        float csum = 0.f;
#pragma unroll
        for (int pb = 0; pb < 4; ++pb)
#pragma unroll
            for (int r = 0; r < 4; ++r) {
                float e = __expf(sacc[pb][r] - mnew);
                ep[pb][r] = e;
                csum += e;
            }
        csum += __shfl_xor(csum, 16);
        csum += __shfl_xor(csum, 32);

        if (__all(cm <= m_run)) {
            s_run += csum;                      // max unchanged for every m in wave
        } else {
            float fac = __expf(m_run - mnew);   // first chunk: exp(-inf)=0
            s_run = s_run * fac + csum;
            m_run = mnew;
            float fr[4];
#pragma unroll
            for (int r = 0; r < 4; ++r) fr[r] = __shfl(fac, hi * 4 + r);
#pragma unroll
            for (int db = 0; db < 4; ++db)
#pragma unroll
                for (int r = 0; r < 4; ++r) oacc[db][r] *= fr[r];
        }

        // ---- P frags (A-operand, zero shuffles) + PV ----
#pragma unroll
        for (int ks2 = 0; ks2 < 2; ++ks2) {
            short8 phi8, plo8;
#pragma unroll
            for (int e = 0; e < 8; ++e) {
                float pv = ep[ks2 * 2 + (e >> 2)][e & 3];
                ushort_t hh = f2bf(pv);
                phi8[e] = (short)hh;
                plo8[e] = (short)f2bf(pv - bf2f(hh));
            }
#pragma unroll
            for (int db = 0; db < 4; ++db) {
                const ushort_t* vp = Vc + (ks2 * 4 + db) * 1024 + l * 8;
                short8 vhi = *(const short8*)vp;
                short8 vlo = *(const short8*)(vp + 512);
                oacc[db] = MFMA(phi8, vhi, oacc[db]);
                oacc[db] = MFMA(plo8, vhi, oacc[db]);
                oacc[db] = MFMA(phi8, vlo, oacc[db]);
            }
        }
    }

    if (hi == 0) { lds_mr[w * 16 + lo] = m_run; lds_sr[w * 16 + lo] = s_run; }

    // ---- phase 2: single attn pass -> final M,Z, attn_out ----
    const float4* abase = (const float4*)(attn + ((size_t)bh * MM + m0) * SPAN);
    float4*       obase = (float4*)(attn_out + ((size_t)bh * MM + m0) * SPAN);
    for (int r = 0; r < 16; ++r) {
        const float4* arow = abase + (size_t)r * 256;
        float4 av[4];
#pragma unroll
        for (int j = 0; j < 4; ++j) av[j] = arow[j * 64 + l];
        float mx = -INFINITY;
#pragma unroll
        for (int j = 0; j < 4; ++j) {
            av[j].x *= 0.125f; av[j].y *= 0.125f; av[j].z *= 0.125f; av[j].w *= 0.125f;
            mx = fmaxf(mx, fmaxf(fmaxf(av[j].x, av[j].y), fmaxf(av[j].z, av[j].w)));
        }
#pragma unroll
        for (int s = 1; s < 64; s <<= 1) mx = fmaxf(mx, __shfl_xor(mx, s));
        float mr = lds_mr[w * 16 + r], sr = lds_sr[w * 16 + r];
        float M = fmaxf(mx, mr);
        float sm = 0.f;
#pragma unroll
        for (int j = 0; j < 4; ++j) {
            av[j].x = __expf(av[j].x - M); sm += av[j].x;
            av[j].y = __expf(av[j].y - M); sm += av[j].y;
            av[j].z = __expf(av[j].z - M); sm += av[j].z;
            av[j].w = __expf(av[j].w - M); sm += av[j].w;
        }
#pragma unroll
        for (int s = 1; s < 64; s <<= 1) sm += __shfl_xor(sm, s);
        float Z  = sr * __expf(mr - M) + sm;
        float iZ = 1.f / Z;
        float4* orow = obase + (size_t)r * 256;
#pragma unroll
        for (int j = 0; j < 4; ++j) {
            float4 o;
            o.x = av[j].x * iZ; o.y = av[j].y * iZ; o.z = av[j].z * iZ; o.w = av[j].w * iZ;
            orow[j * 64 + l] = o;
        }
        if (l == 0) { lds_M[w * 16 + r] = M; lds_Z[w * 16 + r] = Z; }
    }

    // ---- out = oacc * 32*exp(m_run - M)/Z ----
#pragma unroll
    for (int reg = 0; reg < 4; ++reg) {
        int rr = hi * 4 + reg;
        float mr = lds_mr[w * 16 + rr];
        float M  = lds_M[w * 16 + rr];
        float Z  = lds_Z[w * 16 + rr];
        float sc = 32.f * __expf(mr - M) / Z;
        size_t ro = ((size_t)bh * MM + m0 + rr) * DD + lo;
#pragma unroll
        for (int db = 0; db < 4; ++db)
            out[ro + db * 16] = oacc[db][reg] * sc;
    }
}

// ---------------- fallback (round-1 fp32 kernel) if ws too small ----------------
__launch_bounds__(256)
__global__ void pm_fallback(const float* __restrict__ q,
                            const float* __restrict__ attn,
                            const float* __restrict__ key,
                            const float* __restrict__ val,
                            float* __restrict__ attn_out,
                            float* __restrict__ out)
{
    __shared__ float qs[64][68];
    __shared__ float ks[64][68];
    __shared__ float vs[64][DD];
    __shared__ float sc[64][66];
    __shared__ float rmax[64];
    __shared__ float rsum[64];

    const int t    = threadIdx.x;
    const int bh   = blockIdx.y;
    const int tile = blockIdx.x;
    const int h    = bh & (NH - 1);
    const int m0   = tile * 64;
    const int tr   = t >> 4;
    const int tc   = t & 15;
    const int r0   = tr * 4;
    const int c0   = tc * 4;
    const int lane = t & 63;
    const int wave = t >> 6;

    const size_t qbase = (size_t)bh * MM * DD + (size_t)m0 * DD;
    const size_t abase = (size_t)bh * MM * SPAN + (size_t)m0 * SPAN;
    const size_t kbase = (size_t)h * DD * PP;
    const size_t vbase = (size_t)h * PP * DD;

#pragma unroll
    for (int j = 0; j < 16; ++j) {
        int idx = j * 256 + t;
        int r = idx >> 6, d = idx & 63;
        qs[r][d] = q[qbase + (size_t)r * DD + d];
    }
    for (int rr = 0; rr < 16; ++rr) {
        int r = wave * 16 + rr;
        const float* arow = attn + abase + (size_t)r * SPAN;
        float av[16];
        float mx = -INFINITY;
#pragma unroll
        for (int j = 0; j < 16; ++j) { av[j] = arow[j * 64 + lane] * 0.125f; mx = fmaxf(mx, av[j]); }
#pragma unroll
        for (int s = 32; s; s >>= 1) mx = fmaxf(mx, __shfl_xor(mx, s));
        float sm = 0.f;
#pragma unroll
        for (int j = 0; j < 16; ++j) sm += __expf(av[j] - mx);
#pragma unroll
        for (int s = 32; s; s >>= 1) sm += __shfl_xor(sm, s);
        if (lane == 0) { rmax[r] = mx; rsum[r] = sm; }
    }
    __syncthreads();
    for (int p0 = 0; p0 < PP; p0 += 64) {
        if (p0) __syncthreads();
#pragma unroll
        for (int j = 0; j < 16; ++j) {
            int idx = j * 256 + t;
            int d = idx >> 6, pc = idx & 63;
            ks[pc][d] = key[kbase + (size_t)d * PP + p0 + pc];
        }
        __syncthreads();
        float acc[4][4] = {};
#pragma unroll
        for (int d0 = 0; d0 < DD; d0 += 4) {
            float4 q4[4], k4[4];
#pragma unroll
            for (int rr = 0; rr < 4; ++rr) q4[rr] = *(const float4*)&qs[r0 + rr][d0];
#pragma unroll
            for (int cc = 0; cc < 4; ++cc) k4[cc] = *(const float4*)&ks[c0 + cc][d0];
#pragma unroll
            for (int rr = 0; rr < 4; ++rr)
#pragma unroll
                for (int cc = 0; cc < 4; ++cc)
                    acc[rr][cc] += q4[rr].x * k4[cc].x + q4[rr].y * k4[cc].y
                                 + q4[rr].z * k4[cc].z + q4[rr].w * k4[cc].w;
        }
#pragma unroll
        for (int rr = 0; rr < 4; ++rr) {
            float mx = fmaxf(fmaxf(acc[rr][0], acc[rr][1]), fmaxf(acc[rr][2], acc[rr][3]));
#pragma unroll
            for (int s = 8; s; s >>= 1) mx = fmaxf(mx, __shfl_xor(mx, s));
            float sm = 0.f;
#pragma unroll
            for (int cc = 0; cc < 4; ++cc) sm += __expf(acc[rr][cc] - mx);
#pragma unroll
            for (int s = 8; s; s >>= 1) sm += __shfl_xor(sm, s);
            if (tc == 0) {
                int r = r0 + rr;
                float om = rmax[r], os = rsum[r];
                float nm = fmaxf(om, mx);
                rsum[r] = os * __expf(om - nm) + sm * __expf(mx - nm);
                rmax[r] = nm;
            }
        }
    }
    __syncthreads();
    for (int rr = 0; rr < 16; ++rr) {
        int r = wave * 16 + rr;
        float Mx = rmax[r];
        float iZ = 1.0f / rsum[r];
        const float* arow = attn + abase + (size_t)r * SPAN;
        float* orow = attn_out + abase + (size_t)r * SPAN;
#pragma unroll
        for (int j = 0; j < 16; ++j) {
            float a = arow[j * 64 + lane] * 0.125f;
            orow[j * 64 + lane] = __expf(a - Mx) * iZ;
        }
    }
    float acc2[4][4] = {};
    for (int p0 = 0; p0 < PP; p0 += 64) {
        __syncthreads();
#pragma unroll
        for (int j = 0; j < 16; ++j) {
            int idx = j * 256 + t;
            int d = idx >> 6, pc = idx & 63;
            ks[pc][d] = key[kbase + (size_t)d * PP + p0 + pc];
        }
#pragma unroll
        for (int j = 0; j < 16; ++j) {
            int idx = j * 256 + t;
            int pc = idx >> 6, d = idx & 63;
            vs[pc][d] = val[vbase + (size_t)(p0 + pc) * DD + d];
        }
        __syncthreads();
        float acc[4][4] = {};
#pragma unroll
        for (int d0 = 0; d0 < DD; d0 += 4) {
            float4 q4[4], k4[4];
#pragma unroll
            for (int rr = 0; rr < 4; ++rr) q4[rr] = *(const float4*)&qs[r0 + rr][d0];
#pragma unroll
            for (int cc = 0; cc < 4; ++cc) k4[cc] = *(const float4*)&ks[c0 + cc][d0];
#pragma unroll
            for (int rr = 0; rr < 4; ++rr)
#pragma unroll
                for (int cc = 0; cc < 4; ++cc)
                    acc[rr][cc] += q4[rr].x * k4[cc].x + q4[rr].y * k4[cc].y
                                 + q4[rr].z * k4[cc].z + q4[rr].w * k4[cc].w;
        }
#pragma unroll
        for (int rr = 0; rr < 4; ++rr) {
            float Mx = rmax[r0 + rr];
#pragma unroll
            for (int cc = 0; cc < 4; ++cc)
                sc[r0 + rr][c0 + cc] = __expf(acc[rr][cc] - Mx);
        }
        __syncthreads();
        for (int pc = 0; pc < 64; ++pc) {
            float4 v4 = *(const float4*)&vs[pc][tc * 4];
#pragma unroll
            for (int rr = 0; rr < 4; ++rr) {
                float pr = sc[r0 + rr][pc];
                acc2[rr][0] += pr * v4.x;
                acc2[rr][1] += pr * v4.y;
                acc2[rr][2] += pr * v4.z;
                acc2[rr][3] += pr * v4.w;
            }
        }
    }
#pragma unroll
    for (int rr = 0; rr < 4; ++rr) {
        int r = r0 + rr;
        float s = 32.0f / rsum[r];
        float4 o;
        o.x = acc2[rr][0] * s; o.y = acc2[rr][1] * s;
        o.z = acc2[rr][2] * s; o.w = acc2[rr][3] * s;
        *(float4*)&out[(size_t)bh * MM * DD + (size_t)(m0 + r) * DD + tc * 4] = o;
    }
}

extern "C" void kernel_launch(void* const* d_in, const int* in_sizes, int n_in,
                              void* d_out, int out_size, void* d_ws, size_t ws_size,
                              hipStream_t stream) {
    const float* q    = (const float*)d_in[0];
    const float* attn = (const float*)d_in[1];
    const float* key  = (const float*)d_in[2];
    const float* val  = (const float*)d_in[3];
    float* attn_out = (float*)d_out;
    float* out      = (float*)d_out + (size_t)BH * MM * SPAN;

    if (ws_size >= WS_NEED) {
        ushort_t* ws = (ushort_t*)d_ws;
        pm_pre<<<3072, 256, 0, stream>>>(q, key, val, ws);
        pm_main<<<512, 256, 0, stream>>>(attn, ws, attn_out, out);
    } else {
        dim3 grid(MM / 64, BH);
        pm_fallback<<<grid, 256, 0, stream>>>(q, attn, key, val, attn_out, out);
    }
}

// Round 3
// 103.557 us; speedup vs baseline: 5.5282x; 1.2001x over previous
//
#include <hip/hip_runtime.h>
#include <hip/hip_bf16.h>
#include <math.h>

#define BH   32
#define NH   16
#define MM   1024
#define DD   64
#define PP   1024
#define SPAN 1024

typedef unsigned short ushort_t;
typedef __attribute__((ext_vector_type(8))) short  short8;
typedef __attribute__((ext_vector_type(4))) float  f32x4;

#define MFMA(a,b,c) __builtin_amdgcn_mfma_f32_16x16x32_bf16(a,b,c,0,0,0)

// ws: K/V fragment blobs only. Chunk blob (h,c) = 16384 ushorts (32 KB):
//   [0,8192)    K frags: (pb*2+ks)*1024 + l*8  (hi), +512 (lo)
//   [8192,16384) V frags: 8192 + (ks2*4+db)*1024 + l*8 (hi), +512 (lo)
#define WS_NEED (8388608ull)   // 16 h * 16 c * 32 KB

__device__ __forceinline__ ushort_t f2bf(float x) {
    __hip_bfloat16 b = __float2bfloat16(x);
    return __builtin_bit_cast(unsigned short, b);
}
__device__ __forceinline__ float bf2f(ushort_t u) {
    __hip_bfloat16 b = __builtin_bit_cast(__hip_bfloat16, u);
    return __bfloat162float(b);
}

// ---------------- pre-kernel: split-bf16 K/V fragment packing ----------------
// blocks [0,512): key -> K frag blobs: slot(l,e) = key[h][ks*32+(l>>4)*8+e][c*64+pb*16+(l&15)]
// blocks [512,1024): val -> V frag blobs: slot(l,e) = val[h][c*64+ks2*32+(l>>4)*4+(e&3)+16*(e>>2)][db*16+(l&15)]
__launch_bounds__(256)
__global__ void pm_pre(const float* __restrict__ key,
                       const float* __restrict__ val,
                       ushort_t* __restrict__ wsKV)
{
    int bi = blockIdx.x, t = threadIdx.x;
    if (bi < 512) {
        int id = bi * 256 + t;                        // 131072 total
        int l  = id & 63;
        int ks = (id >> 6) & 1;
        int pb = (id >> 7) & 3;
        int c  = (id >> 9) & 15;
        int h  = id >> 13;
        int p     = c * 64 + pb * 16 + (l & 15);
        int dbase = ks * 32 + (l >> 4) * 8;
        size_t fo = (size_t)(h * 16 + c) * 16384 + (size_t)(pb * 2 + ks) * 1024 + (size_t)l * 8;
#pragma unroll
        for (int e = 0; e < 8; ++e) {
            float x = key[(size_t)(h * 64 + dbase + e) * PP + p];
            ushort_t hh = f2bf(x);
            wsKV[fo + e]       = hh;
            wsKV[fo + 512 + e] = f2bf(x - bf2f(hh));
        }
    } else {
        int id = (bi - 512) * 256 + t;                // 131072 total
        int l   = id & 63;
        int db  = (id >> 6) & 3;
        int ks2 = (id >> 8) & 1;
        int c   = (id >> 9) & 15;
        int h   = id >> 13;
        int d = db * 16 + (l & 15);
        size_t fo = (size_t)(h * 16 + c) * 16384 + 8192 + (size_t)(ks2 * 4 + db) * 1024 + (size_t)l * 8;
#pragma unroll
        for (int e = 0; e < 8; ++e) {
            int p = c * 64 + ks2 * 32 + ((l >> 4) * 4) + (e & 3) + 16 * (e >> 2);
            float x = val[(size_t)(h * PP + p) * DD + d];
            ushort_t hh = f2bf(x);
            wsKV[fo + e]       = hh;
            wsKV[fo + 512 + e] = f2bf(x - bf2f(hh));
        }
    }
}

// ---------------- main kernel ----------------
__launch_bounds__(256)
__global__ void pm_main(const float* __restrict__ q,
                        const float* __restrict__ attn,
                        const ushort_t* __restrict__ wsKV,
                        float* __restrict__ attn_out,
                        float* __restrict__ out)
{
    __shared__ ushort_t kvbuf[2][16384];   // 2 x 32 KB double buffer
    __shared__ float lds_mr[64], lds_sr[64], lds_M[64], lds_Z[64];

    const int t  = threadIdx.x;
    const int w  = t >> 6;
    const int l  = t & 63;
    const int bi = blockIdx.x;
    const int bh   = bi & 31;     // bi%8 == bh%8 -> same-h blocks share an XCD's L2
    const int tile = bi >> 5;
    const int h  = bh & (NH - 1);
    const int hi = l >> 4;
    const int lo = l & 15;
    const int m0 = tile * 64 + w * 16;

    // ---- Q fragments from global fp32 (B-operand of S^T mfma) ----
    // slot(l,e) = Q[m0+(l&15)][ks*32 + (l>>4)*8 + e], split hi/lo bf16
    short8 qf[2][2];
    {
        const float* qr = q + ((size_t)bh * MM + m0 + lo) * DD + hi * 8;
#pragma unroll
        for (int ks = 0; ks < 2; ++ks) {
            float4 a = *(const float4*)(qr + ks * 32);
            float4 b = *(const float4*)(qr + ks * 32 + 4);
            float f[8] = {a.x, a.y, a.z, a.w, b.x, b.y, b.z, b.w};
            short8 qh, ql;
#pragma unroll
            for (int e = 0; e < 8; ++e) {
                ushort_t hh = f2bf(f[e]);
                qh[e] = (short)hh;
                ql[e] = (short)f2bf(f[e] - bf2f(hh));
            }
            qf[ks][0] = qh;
            qf[ks][1] = ql;
        }
    }

    const ushort_t* KVb = wsKV + (size_t)h * (16 * 16384);

    // stage chunk c into kvbuf[b]: 32 KB, 8 x global_load_lds(16B) per thread
    auto STAGE = [&](int b, int c) {
        const char* src = (const char*)(KVb + (size_t)c * 16384) + w * 8192 + l * 16;
        char* dst = (char*)&kvbuf[b][0] + w * 8192;
#pragma unroll
        for (int j = 0; j < 8; ++j)
            __builtin_amdgcn_global_load_lds(
                (const __attribute__((address_space(1))) void*)(src + j * 1024),
                (__attribute__((address_space(3))) void*)(dst + j * 1024),
                16, 0, 0);
    };

    f32x4 oacc[4] = {{0.f,0.f,0.f,0.f},{0.f,0.f,0.f,0.f},{0.f,0.f,0.f,0.f},{0.f,0.f,0.f,0.f}};
    float m_run = -INFINITY, s_run = 0.f;

    STAGE(0, 0);
    __syncthreads();

    for (int c = 0; c < 16; ++c) {
        const int cur = c & 1;
        if (c < 15) STAGE(cur ^ 1, c + 1);

        const ushort_t* Kc = &kvbuf[cur][0];
        const ushort_t* Vc = Kc + 8192;

        // ---- S^T chunk: D[p][m], p = c*64 + pb*16 + hi*4 + reg, m = lo ----
        f32x4 sacc[4] = {{0.f,0.f,0.f,0.f},{0.f,0.f,0.f,0.f},{0.f,0.f,0.f,0.f},{0.f,0.f,0.f,0.f}};
#pragma unroll
        for (int pb = 0; pb < 4; ++pb) {
#pragma unroll
            for (int ks = 0; ks < 2; ++ks) {
                const ushort_t* fp = Kc + (pb * 2 + ks) * 1024 + l * 8;
                short8 khi = *(const short8*)fp;
                short8 klo = *(const short8*)(fp + 512);
                sacc[pb] = MFMA(khi, qf[ks][0], sacc[pb]);
                sacc[pb] = MFMA(khi, qf[ks][1], sacc[pb]);
                sacc[pb] = MFMA(klo, qf[ks][0], sacc[pb]);
            }
        }

        // ---- online softmax over the 64-p chunk (per m = lo, replicated over hi) ----
        float cm = -INFINITY;
#pragma unroll
        for (int pb = 0; pb < 4; ++pb)
#pragma unroll
            for (int r = 0; r < 4; ++r) cm = fmaxf(cm, sacc[pb][r]);
        cm = fmaxf(cm, __shfl_xor(cm, 16));
        cm = fmaxf(cm, __shfl_xor(cm, 32));
        float mnew = fmaxf(m_run, cm);

        float ep[4][4];
        float csum = 0.f;
#pragma unroll
        for (int pb = 0; pb < 4; ++pb)
#pragma unroll
            for (int r = 0; r < 4; ++r) {
                float e = __expf(sacc[pb][r] - mnew);
                ep[pb][r] = e;
                csum += e;
            }
        csum += __shfl_xor(csum, 16);
        csum += __shfl_xor(csum, 32);

        if (__all(cm <= m_run)) {
            s_run += csum;
        } else {
            float fac = __expf(m_run - mnew);   // first chunk: exp(-inf)=0
            s_run = s_run * fac + csum;
            m_run = mnew;
            float fr[4];
#pragma unroll
            for (int r = 0; r < 4; ++r) fr[r] = __shfl(fac, hi * 4 + r);
#pragma unroll
            for (int db = 0; db < 4; ++db)
#pragma unroll
                for (int r = 0; r < 4; ++r) oacc[db][r] *= fr[r];
        }

        // ---- P frags (A-operand, zero shuffles) + PV ----
#pragma unroll
        for (int ks2 = 0; ks2 < 2; ++ks2) {
            short8 phi8, plo8;
#pragma unroll
            for (int e = 0; e < 8; ++e) {
                float pv = ep[ks2 * 2 + (e >> 2)][e & 3];
                ushort_t hh = f2bf(pv);
                phi8[e] = (short)hh;
                plo8[e] = (short)f2bf(pv - bf2f(hh));
            }
#pragma unroll
            for (int db = 0; db < 4; ++db) {
                const ushort_t* vp = Vc + (ks2 * 4 + db) * 1024 + l * 8;
                short8 vhi = *(const short8*)vp;
                short8 vlo = *(const short8*)(vp + 512);
                oacc[db] = MFMA(phi8, vhi, oacc[db]);
                oacc[db] = MFMA(plo8, vhi, oacc[db]);
                oacc[db] = MFMA(phi8, vlo, oacc[db]);
            }
        }

        __syncthreads();   // buf[cur^1] staged; all waves done reading buf[cur]
    }

    if (hi == 0) { lds_mr[w * 16 + lo] = m_run; lds_sr[w * 16 + lo] = s_run; }

    // ---- phase 2: single attn pass -> final M,Z, attn_out (nontemporal streams) ----
    const f32x4* abase = (const f32x4*)(attn + ((size_t)bh * MM + m0) * SPAN);
    f32x4*       obase = (f32x4*)(attn_out + ((size_t)bh * MM + m0) * SPAN);
    for (int r = 0; r < 16; ++r) {
        const f32x4* arow = abase + (size_t)r * 256;
        f32x4 av[4];
#pragma unroll
        for (int j = 0; j < 4; ++j) av[j] = __builtin_nontemporal_load(arow + j * 64 + l);
        float mx = -INFINITY;
#pragma unroll
        for (int j = 0; j < 4; ++j) {
            av[j] *= 0.125f;
            mx = fmaxf(mx, fmaxf(fmaxf(av[j][0], av[j][1]), fmaxf(av[j][2], av[j][3])));
        }
#pragma unroll
        for (int s = 1; s < 64; s <<= 1) mx = fmaxf(mx, __shfl_xor(mx, s));
        float mr = lds_mr[w * 16 + r], sr = lds_sr[w * 16 + r];
        float M = fmaxf(mx, mr);
        float sm = 0.f;
#pragma unroll
        for (int j = 0; j < 4; ++j) {
#pragma unroll
            for (int e = 0; e < 4; ++e) {
                av[j][e] = __expf(av[j][e] - M);
                sm += av[j][e];
            }
        }
#pragma unroll
        for (int s = 1; s < 64; s <<= 1) sm += __shfl_xor(sm, s);
        float Z  = sr * __expf(mr - M) + sm;
        float iZ = 1.f / Z;
        f32x4* orow = obase + (size_t)r * 256;
#pragma unroll
        for (int j = 0; j < 4; ++j)
            __builtin_nontemporal_store(av[j] * iZ, orow + j * 64 + l);
        if (l == 0) { lds_M[w * 16 + r] = M; lds_Z[w * 16 + r] = Z; }
    }

    // ---- out = oacc * 32*exp(m_run - M)/Z ----
#pragma unroll
    for (int reg = 0; reg < 4; ++reg) {
        int rr = hi * 4 + reg;
        float mr = lds_mr[w * 16 + rr];
        float M  = lds_M[w * 16 + rr];
        float Z  = lds_Z[w * 16 + rr];
        float sc = 32.f * __expf(mr - M) / Z;
        size_t ro = ((size_t)bh * MM + m0 + rr) * DD + lo;
#pragma unroll
        for (int db = 0; db < 4; ++db)
            out[ro + db * 16] = oacc[db][reg] * sc;
    }
}

// ---------------- fallback (fp32 VALU) if ws too small ----------------
__launch_bounds__(256)
__global__ void pm_fallback(const float* __restrict__ q,
                            const float* __restrict__ attn,
                            const float* __restrict__ key,
                            const float* __restrict__ val,
                            float* __restrict__ attn_out,
                            float* __restrict__ out)
{
    __shared__ float qs[64][68];
    __shared__ float ks[64][68];
    __shared__ float vs[64][DD];
    __shared__ float sc[64][66];
    __shared__ float rmax[64];
    __shared__ float rsum[64];

    const int t    = threadIdx.x;
    const int bh   = blockIdx.y;
    const int tile = blockIdx.x;
    const int h    = bh & (NH - 1);
    const int m0   = tile * 64;
    const int tr   = t >> 4;
    const int tc   = t & 15;
    const int r0   = tr * 4;
    const int c0   = tc * 4;
    const int lane = t & 63;
    const int wave = t >> 6;

    const size_t qbase = (size_t)bh * MM * DD + (size_t)m0 * DD;
    const size_t abase = (size_t)bh * MM * SPAN + (size_t)m0 * SPAN;
    const size_t kbase = (size_t)h * DD * PP;
    const size_t vbase = (size_t)h * PP * DD;

#pragma unroll
    for (int j = 0; j < 16; ++j) {
        int idx = j * 256 + t;
        int r = idx >> 6, d = idx & 63;
        qs[r][d] = q[qbase + (size_t)r * DD + d];
    }
    for (int rr = 0; rr < 16; ++rr) {
        int r = wave * 16 + rr;
        const float* arow = attn + abase + (size_t)r * SPAN;
        float av[16];
        float mx = -INFINITY;
#pragma unroll
        for (int j = 0; j < 16; ++j) { av[j] = arow[j * 64 + lane] * 0.125f; mx = fmaxf(mx, av[j]); }
#pragma unroll
        for (int s = 32; s; s >>= 1) mx = fmaxf(mx, __shfl_xor(mx, s));
        float sm = 0.f;
#pragma unroll
        for (int j = 0; j < 16; ++j) sm += __expf(av[j] - mx);
#pragma unroll
        for (int s = 32; s; s >>= 1) sm += __shfl_xor(sm, s);
        if (lane == 0) { rmax[r] = mx; rsum[r] = sm; }
    }
    __syncthreads();
    for (int p0 = 0; p0 < PP; p0 += 64) {
        if (p0) __syncthreads();
#pragma unroll
        for (int j = 0; j < 16; ++j) {
            int idx = j * 256 + t;
            int d = idx >> 6, pc = idx & 63;
            ks[pc][d] = key[kbase + (size_t)d * PP + p0 + pc];
        }
        __syncthreads();
        float acc[4][4] = {};
#pragma unroll
        for (int d0 = 0; d0 < DD; d0 += 4) {
            float4 q4[4], k4[4];
#pragma unroll
            for (int rr = 0; rr < 4; ++rr) q4[rr] = *(const float4*)&qs[r0 + rr][d0];
#pragma unroll
            for (int cc = 0; cc < 4; ++cc) k4[cc] = *(const float4*)&ks[c0 + cc][d0];
#pragma unroll
            for (int rr = 0; rr < 4; ++rr)
#pragma unroll
                for (int cc = 0; cc < 4; ++cc)
                    acc[rr][cc] += q4[rr].x * k4[cc].x + q4[rr].y * k4[cc].y
                                 + q4[rr].z * k4[cc].z + q4[rr].w * k4[cc].w;
        }
#pragma unroll
        for (int rr = 0; rr < 4; ++rr) {
            float mx = fmaxf(fmaxf(acc[rr][0], acc[rr][1]), fmaxf(acc[rr][2], acc[rr][3]));
#pragma unroll
            for (int s = 8; s; s >>= 1) mx = fmaxf(mx, __shfl_xor(mx, s));
            float sm = 0.f;
#pragma unroll
            for (int cc = 0; cc < 4; ++cc) sm += __expf(acc[rr][cc] - mx);
#pragma unroll
            for (int s = 8; s; s >>= 1) sm += __shfl_xor(sm, s);
            if (tc == 0) {
                int r = r0 + rr;
                float om = rmax[r], os = rsum[r];
                float nm = fmaxf(om, mx);
                rsum[r] = os * __expf(om - nm) + sm * __expf(mx - nm);
                rmax[r] = nm;
            }
        }
    }
    __syncthreads();
    for (int rr = 0; rr < 16; ++rr) {
        int r = wave * 16 + rr;
        float Mx = rmax[r];
        float iZ = 1.0f / rsum[r];
        const float* arow = attn + abase + (size_t)r * SPAN;
        float* orow = attn_out + abase + (size_t)r * SPAN;
#pragma unroll
        for (int j = 0; j < 16; ++j) {
            float a = arow[j * 64 + lane] * 0.125f;
            orow[j * 64 + lane] = __expf(a - Mx) * iZ;
        }
    }
    float acc2[4][4] = {};
    for (int p0 = 0; p0 < PP; p0 += 64) {
        __syncthreads();
#pragma unroll
        for (int j = 0; j < 16; ++j) {
            int idx = j * 256 + t;
            int d = idx >> 6, pc = idx & 63;
            ks[pc][d] = key[kbase + (size_t)d * PP + p0 + pc];
        }
#pragma unroll
        for (int j = 0; j < 16; ++j) {
            int idx = j * 256 + t;
            int pc = idx >> 6, d = idx & 63;
            vs[pc][d] = val[vbase + (size_t)(p0 + pc) * DD + d];
        }
        __syncthreads();
        float acc[4][4] = {};
#pragma unroll
        for (int d0 = 0; d0 < DD; d0 += 4) {
            float4 q4[4], k4[4];
#pragma unroll
            for (int rr = 0; rr < 4; ++rr) q4[rr] = *(const float4*)&qs[r0 + rr][d0];
#pragma unroll
            for (int cc = 0; cc < 4; ++cc) k4[cc] = *(const float4*)&ks[c0 + cc][d0];
#pragma unroll
            for (int rr = 0; rr < 4; ++rr)
#pragma unroll
                for (int cc = 0; cc < 4; ++cc)
                    acc[rr][cc] += q4[rr].x * k4[cc].x + q4[rr].y * k4[cc].y
                                 + q4[rr].z * k4[cc].z + q4[rr].w * k4[cc].w;
        }
#pragma unroll
        for (int rr = 0; rr < 4; ++rr) {
            float Mx = rmax[r0 + rr];
#pragma unroll
            for (int cc = 0; cc < 4; ++cc)
                sc[r0 + rr][c0 + cc] = __expf(acc[rr][cc] - Mx);
        }
        __syncthreads();
        for (int pc = 0; pc < 64; ++pc) {
            float4 v4 = *(const float4*)&vs[pc][tc * 4];
#pragma unroll
            for (int rr = 0; rr < 4; ++rr) {
                float pr = sc[r0 + rr][pc];
                acc2[rr][0] += pr * v4.x;
                acc2[rr][1] += pr * v4.y;
                acc2[rr][2] += pr * v4.z;
                acc2[rr][3] += pr * v4.w;
            }
        }
    }
#pragma unroll
    for (int rr = 0; rr < 4; ++rr) {
        int r = r0 + rr;
        float s = 32.0f / rsum[r];
        float4 o;
        o.x = acc2[rr][0] * s; o.y = acc2[rr][1] * s;
        o.z = acc2[rr][2] * s; o.w = acc2[rr][3] * s;
        *(float4*)&out[(size_t)bh * MM * DD + (size_t)(m0 + r) * DD + tc * 4] = o;
    }
}

extern "C" void kernel_launch(void* const* d_in, const int* in_sizes, int n_in,
                              void* d_out, int out_size, void* d_ws, size_t ws_size,
                              hipStream_t stream) {
    const float* q    = (const float*)d_in[0];
    const float* attn = (const float*)d_in[1];
    const float* key  = (const float*)d_in[2];
    const float* val  = (const float*)d_in[3];
    float* attn_out = (float*)d_out;
    float* out      = (float*)d_out + (size_t)BH * MM * SPAN;

    if (ws_size >= WS_NEED) {
        ushort_t* ws = (ushort_t*)d_ws;
        pm_pre<<<1024, 256, 0, stream>>>(key, val, ws);
        pm_main<<<512, 256, 0, stream>>>(q, attn, ws, attn_out, out);
    } else {
        dim3 grid(MM / 64, BH);
        pm_fallback<<<grid, 256, 0, stream>>>(q, attn, key, val, attn_out, out);
    }
}

// Round 4
// 89.619 us; speedup vs baseline: 6.3880x; 1.1555x over previous
//
#include <hip/hip_runtime.h>
#include <hip/hip_bf16.h>
#include <math.h>

#define BH   32
#define NH   16
#define MM   1024
#define DD   64
#define PP   1024
#define SPAN 1024

typedef unsigned short ushort_t;
typedef __attribute__((ext_vector_type(8))) short  short8;
typedef __attribute__((ext_vector_type(4))) float  f32x4;

#define MFMA(a,b,c) __builtin_amdgcn_mfma_f32_16x16x32_bf16(a,b,c,0,0,0)

// ws layout:
//   [0, 8 MB)          K/V fragment blobs (ushort), chunk blob (h,c) = 16384 ushorts
//   [8 MB, 8 MB+256KB) per-row [M, 1/Z] float pairs (32768 rows)
#define WS_MIZ_OFF (8388608ull)
#define WS_NEED    (8388608ull + 262144ull)

__device__ __forceinline__ ushort_t f2bf(float x) {
    __hip_bfloat16 b = __float2bfloat16(x);
    return __builtin_bit_cast(unsigned short, b);
}
__device__ __forceinline__ float bf2f(ushort_t u) {
    __hip_bfloat16 b = __builtin_bit_cast(__hip_bfloat16, u);
    return __bfloat162float(b);
}

// ---------------- pre-kernel: split-bf16 K/V fragment packing ----------------
__launch_bounds__(256)
__global__ void pm_pre(const float* __restrict__ key,
                       const float* __restrict__ val,
                       ushort_t* __restrict__ wsKV)
{
    int bi = blockIdx.x, t = threadIdx.x;
    if (bi < 512) {
        int id = bi * 256 + t;
        int l  = id & 63;
        int ks = (id >> 6) & 1;
        int pb = (id >> 7) & 3;
        int c  = (id >> 9) & 15;
        int h  = id >> 13;
        int p     = c * 64 + pb * 16 + (l & 15);
        int dbase = ks * 32 + (l >> 4) * 8;
        size_t fo = (size_t)(h * 16 + c) * 16384 + (size_t)(pb * 2 + ks) * 1024 + (size_t)l * 8;
#pragma unroll
        for (int e = 0; e < 8; ++e) {
            float x = key[(size_t)(h * 64 + dbase + e) * PP + p];
            ushort_t hh = f2bf(x);
            wsKV[fo + e]       = hh;
            wsKV[fo + 512 + e] = f2bf(x - bf2f(hh));
        }
    } else {
        int id = (bi - 512) * 256 + t;
        int l   = id & 63;
        int db  = (id >> 6) & 3;
        int ks2 = (id >> 8) & 1;
        int c   = (id >> 9) & 15;
        int h   = id >> 13;
        int d = db * 16 + (l & 15);
        size_t fo = (size_t)(h * 16 + c) * 16384 + 8192 + (size_t)(ks2 * 4 + db) * 1024 + (size_t)l * 8;
#pragma unroll
        for (int e = 0; e < 8; ++e) {
            int p = c * 64 + ks2 * 32 + ((l >> 4) * 4) + (e & 3) + 16 * (e >> 2);
            float x = val[(size_t)(h * PP + p) * DD + d];
            ushort_t hh = f2bf(x);
            wsKV[fo + e]       = hh;
            wsKV[fo + 512 + e] = f2bf(x - bf2f(hh));
        }
    }
}

// ---------------- main kernel: 4 compute waves + 4 stats waves per block ----------------
__launch_bounds__(512)
__global__ void pm_main(const float* __restrict__ q,
                        const float* __restrict__ attn,
                        const ushort_t* __restrict__ wsKV,
                        float* __restrict__ ws_MiZ,
                        float* __restrict__ out)
{
    __shared__ ushort_t kvbuf[2][16384];   // 2 x 32 KB double buffer
    __shared__ float lds_mx[64], lds_sm[64];

    const int t  = threadIdx.x;
    const int w  = t >> 6;
    const int l  = t & 63;
    const int bi = blockIdx.x;
    const int bh   = bi & 31;     // bi%8 == bh%8 -> same-h blocks share an XCD's L2
    const int tile = bi >> 5;
    const int h  = bh & (NH - 1);
    const int hi = l >> 4;
    const int lo = l & 15;

    if (w < 4) {
        // ================= compute waves: phase-1 flash loop =================
        const int m0 = tile * 64 + w * 16;

        // Q fragments from global fp32 (B-operand of S^T mfma), split hi/lo bf16
        short8 qf[2][2];
        {
            const float* qr = q + ((size_t)bh * MM + m0 + lo) * DD + hi * 8;
#pragma unroll
            for (int ks = 0; ks < 2; ++ks) {
                float4 a = *(const float4*)(qr + ks * 32);
                float4 b = *(const float4*)(qr + ks * 32 + 4);
                float f[8] = {a.x, a.y, a.z, a.w, b.x, b.y, b.z, b.w};
                short8 qh, ql;
#pragma unroll
                for (int e = 0; e < 8; ++e) {
                    ushort_t hh = f2bf(f[e]);
                    qh[e] = (short)hh;
                    ql[e] = (short)f2bf(f[e] - bf2f(hh));
                }
                qf[ks][0] = qh;
                qf[ks][1] = ql;
            }
        }

        const ushort_t* KVb = wsKV + (size_t)h * (16 * 16384);

        auto STAGE = [&](int b, int c) {
            const char* src = (const char*)(KVb + (size_t)c * 16384) + w * 8192 + l * 16;
            char* dst = (char*)&kvbuf[b][0] + w * 8192;
#pragma unroll
            for (int j = 0; j < 8; ++j)
                __builtin_amdgcn_global_load_lds(
                    (const __attribute__((address_space(1))) void*)(src + j * 1024),
                    (__attribute__((address_space(3))) void*)(dst + j * 1024),
                    16, 0, 0);
        };

        f32x4 oacc[4] = {{0.f,0.f,0.f,0.f},{0.f,0.f,0.f,0.f},{0.f,0.f,0.f,0.f},{0.f,0.f,0.f,0.f}};
        float m_run = -INFINITY, s_run = 0.f;

        STAGE(0, 0);
        __syncthreads();

        for (int c = 0; c < 16; ++c) {
            const int cur = c & 1;
            if (c < 15) STAGE(cur ^ 1, c + 1);

            const ushort_t* Kc = &kvbuf[cur][0];
            const ushort_t* Vc = Kc + 8192;

            // ---- S^T chunk: D[p][m], p = c*64 + pb*16 + hi*4 + reg, m = lo ----
            f32x4 sacc[4] = {{0.f,0.f,0.f,0.f},{0.f,0.f,0.f,0.f},{0.f,0.f,0.f,0.f},{0.f,0.f,0.f,0.f}};
            __builtin_amdgcn_s_setprio(1);
#pragma unroll
            for (int pb = 0; pb < 4; ++pb) {
#pragma unroll
                for (int ks = 0; ks < 2; ++ks) {
                    const ushort_t* fp = Kc + (pb * 2 + ks) * 1024 + l * 8;
                    short8 khi = *(const short8*)fp;
                    short8 klo = *(const short8*)(fp + 512);
                    sacc[pb] = MFMA(khi, qf[ks][0], sacc[pb]);
                    sacc[pb] = MFMA(khi, qf[ks][1], sacc[pb]);
                    sacc[pb] = MFMA(klo, qf[ks][0], sacc[pb]);
                }
            }
            __builtin_amdgcn_s_setprio(0);

            // ---- online softmax over the 64-p chunk (per m = lo, replicated over hi) ----
            float cm = -INFINITY;
#pragma unroll
            for (int pb = 0; pb < 4; ++pb)
#pragma unroll
                for (int r = 0; r < 4; ++r) cm = fmaxf(cm, sacc[pb][r]);
            cm = fmaxf(cm, __shfl_xor(cm, 16));
            cm = fmaxf(cm, __shfl_xor(cm, 32));
            float mnew = fmaxf(m_run, cm);

            float ep[4][4];
            float csum = 0.f;
#pragma unroll
            for (int pb = 0; pb < 4; ++pb)
#pragma unroll
                for (int r = 0; r < 4; ++r) {
                    float e = __expf(sacc[pb][r] - mnew);
                    ep[pb][r] = e;
                    csum += e;
                }
            csum += __shfl_xor(csum, 16);
            csum += __shfl_xor(csum, 32);

            if (__all(cm <= m_run)) {
                s_run += csum;
            } else {
                float fac = __expf(m_run - mnew);   // first chunk: exp(-inf)=0
                s_run = s_run * fac + csum;
                m_run = mnew;
                float fr[4];
#pragma unroll
                for (int r = 0; r < 4; ++r) fr[r] = __shfl(fac, hi * 4 + r);
#pragma unroll
                for (int db = 0; db < 4; ++db)
#pragma unroll
                    for (int r = 0; r < 4; ++r) oacc[db][r] *= fr[r];
            }

            // ---- P frags (A-operand, zero shuffles) + PV ----
#pragma unroll
            for (int ks2 = 0; ks2 < 2; ++ks2) {
                short8 phi8, plo8;
#pragma unroll
                for (int e = 0; e < 8; ++e) {
                    float pv = ep[ks2 * 2 + (e >> 2)][e & 3];
                    ushort_t hh = f2bf(pv);
                    phi8[e] = (short)hh;
                    plo8[e] = (short)f2bf(pv - bf2f(hh));
                }
                __builtin_amdgcn_s_setprio(1);
#pragma unroll
                for (int db = 0; db < 4; ++db) {
                    const ushort_t* vp = Vc + (ks2 * 4 + db) * 1024 + l * 8;
                    short8 vhi = *(const short8*)vp;
                    short8 vlo = *(const short8*)(vp + 512);
                    oacc[db] = MFMA(phi8, vhi, oacc[db]);
                    oacc[db] = MFMA(plo8, vhi, oacc[db]);
                    oacc[db] = MFMA(phi8, vlo, oacc[db]);
                }
                __builtin_amdgcn_s_setprio(0);
            }

            __syncthreads();   // buf[cur^1] staged; everyone done with buf[cur]; stats row c published
        }

        // ---- epilogue: merge attn stats (from stats waves) + write out, M/iZ ----
        float mx = lds_mx[w * 16 + lo];
        float sm = lds_sm[w * 16 + lo];
        float M  = fmaxf(mx, m_run);
        float Z  = sm * __expf(mx - M) + s_run * __expf(m_run - M);
        float iZ = 1.f / Z;
        float fac = 32.f * __expf(m_run - M) * iZ;

        if (hi == 0) {
            size_t row = (size_t)bh * MM + m0 + lo;
            ws_MiZ[row * 2]     = M;
            ws_MiZ[row * 2 + 1] = iZ;
        }

        float fr[4];
#pragma unroll
        for (int r = 0; r < 4; ++r) fr[r] = __shfl(fac, hi * 4 + r);
#pragma unroll
        for (int reg = 0; reg < 4; ++reg) {
            size_t ro = ((size_t)bh * MM + m0 + hi * 4 + reg) * DD + lo;
#pragma unroll
            for (int db = 0; db < 4; ++db)
                __builtin_nontemporal_store(oacc[db][reg] * fr[reg], &out[ro + db * 16]);
        }
    } else {
        // ================= stats waves: this block's 64 attn-row max/sum =================
        const int sw = w - 4;
        __syncthreads();                       // matches compute's post-STAGE(0,0) sync
        for (int c = 0; c < 16; ++c) {
            const int m = tile * 64 + sw * 16 + c;
            const f32x4* arow = (const f32x4*)(attn + ((size_t)bh * MM + m) * SPAN);
            f32x4 av[4];
#pragma unroll
            for (int j = 0; j < 4; ++j) av[j] = arow[j * 64 + l];
            float mx = -INFINITY;
#pragma unroll
            for (int j = 0; j < 4; ++j) {
                av[j] *= 0.125f;
                mx = fmaxf(mx, fmaxf(fmaxf(av[j][0], av[j][1]), fmaxf(av[j][2], av[j][3])));
            }
#pragma unroll
            for (int s = 1; s < 64; s <<= 1) mx = fmaxf(mx, __shfl_xor(mx, s));
            float sm = 0.f;
#pragma unroll
            for (int j = 0; j < 4; ++j)
#pragma unroll
                for (int e = 0; e < 4; ++e) sm += __expf(av[j][e] - mx);
#pragma unroll
            for (int s = 1; s < 64; s <<= 1) sm += __shfl_xor(sm, s);
            if (l == 0) { lds_mx[sw * 16 + c] = mx; lds_sm[sw * 16 + c] = sm; }
            __syncthreads();                   // matches compute's end-of-chunk sync
        }
        // no epilogue work
    }
}

// ---------------- normalizer: attn_out = exp(a/8 - M) * iZ (pure streaming) ----------------
__launch_bounds__(256)
__global__ void pm_norm(const float* __restrict__ attn,
                        const float* __restrict__ ws_MiZ,
                        float* __restrict__ attn_out)
{
    const int t = threadIdx.x;
    const int w = t >> 6;
    const int l = t & 63;
    const size_t row = (size_t)blockIdx.x * 4 + w;   // 0..32767

    const float2 mz = ((const float2*)ws_MiZ)[row];
    const float M = mz.x, iZ = mz.y;

    const f32x4* arow = (const f32x4*)(attn + row * SPAN);
    f32x4*       orow = (f32x4*)(attn_out + row * SPAN);
#pragma unroll
    for (int j = 0; j < 4; ++j) {
        f32x4 a = arow[j * 64 + l];
        f32x4 o;
#pragma unroll
        for (int e = 0; e < 4; ++e) o[e] = __expf(a[e] * 0.125f - M) * iZ;
        __builtin_nontemporal_store(o, orow + j * 64 + l);
    }
}

// ---------------- fallback (fp32 VALU) if ws too small ----------------
__launch_bounds__(256)
__global__ void pm_fallback(const float* __restrict__ q,
                            const float* __restrict__ attn,
                            const float* __restrict__ key,
                            const float* __restrict__ val,
                            float* __restrict__ attn_out,
                            float* __restrict__ out)
{
    __shared__ float qs[64][68];
    __shared__ float ks[64][68];
    __shared__ float vs[64][DD];
    __shared__ float sc[64][66];
    __shared__ float rmax[64];
    __shared__ float rsum[64];

    const int t    = threadIdx.x;
    const int bh   = blockIdx.y;
    const int tile = blockIdx.x;
    const int h    = bh & (NH - 1);
    const int m0   = tile * 64;
    const int tr   = t >> 4;
    const int tc   = t & 15;
    const int r0   = tr * 4;
    const int c0   = tc * 4;
    const int lane = t & 63;
    const int wave = t >> 6;

    const size_t qbase = (size_t)bh * MM * DD + (size_t)m0 * DD;
    const size_t abase = (size_t)bh * MM * SPAN + (size_t)m0 * SPAN;
    const size_t kbase = (size_t)h * DD * PP;
    const size_t vbase = (size_t)h * PP * DD;

#pragma unroll
    for (int j = 0; j < 16; ++j) {
        int idx = j * 256 + t;
        int r = idx >> 6, d = idx & 63;
        qs[r][d] = q[qbase + (size_t)r * DD + d];
    }
    for (int rr = 0; rr < 16; ++rr) {
        int r = wave * 16 + rr;
        const float* arow = attn + abase + (size_t)r * SPAN;
        float av[16];
        float mx = -INFINITY;
#pragma unroll
        for (int j = 0; j < 16; ++j) { av[j] = arow[j * 64 + lane] * 0.125f; mx = fmaxf(mx, av[j]); }
#pragma unroll
        for (int s = 32; s; s >>= 1) mx = fmaxf(mx, __shfl_xor(mx, s));
        float sm = 0.f;
#pragma unroll
        for (int j = 0; j < 16; ++j) sm += __expf(av[j] - mx);
#pragma unroll
        for (int s = 32; s; s >>= 1) sm += __shfl_xor(sm, s);
        if (lane == 0) { rmax[r] = mx; rsum[r] = sm; }
    }
    __syncthreads();
    for (int p0 = 0; p0 < PP; p0 += 64) {
        if (p0) __syncthreads();
#pragma unroll
        for (int j = 0; j < 16; ++j) {
            int idx = j * 256 + t;
            int d = idx >> 6, pc = idx & 63;
            ks[pc][d] = key[kbase + (size_t)d * PP + p0 + pc];
        }
        __syncthreads();
        float acc[4][4] = {};
#pragma unroll
        for (int d0 = 0; d0 < DD; d0 += 4) {
            float4 q4[4], k4[4];
#pragma unroll
            for (int rr = 0; rr < 4; ++rr) q4[rr] = *(const float4*)&qs[r0 + rr][d0];
#pragma unroll
            for (int cc = 0; cc < 4; ++cc) k4[cc] = *(const float4*)&ks[c0 + cc][d0];
#pragma unroll
            for (int rr = 0; rr < 4; ++rr)
#pragma unroll
                for (int cc = 0; cc < 4; ++cc)
                    acc[rr][cc] += q4[rr].x * k4[cc].x + q4[rr].y * k4[cc].y
                                 + q4[rr].z * k4[cc].z + q4[rr].w * k4[cc].w;
        }
#pragma unroll
        for (int rr = 0; rr < 4; ++rr) {
            float mx = fmaxf(fmaxf(acc[rr][0], acc[rr][1]), fmaxf(acc[rr][2], acc[rr][3]));
#pragma unroll
            for (int s = 8; s; s >>= 1) mx = fmaxf(mx, __shfl_xor(mx, s));
            float sm = 0.f;
#pragma unroll
            for (int cc = 0; cc < 4; ++cc) sm += __expf(acc[rr][cc] - mx);
#pragma unroll
            for (int s = 8; s; s >>= 1) sm += __shfl_xor(sm, s);
            if (tc == 0) {
                int r = r0 + rr;
                float om = rmax[r], os = rsum[r];
                float nm = fmaxf(om, mx);
                rsum[r] = os * __expf(om - nm) + sm * __expf(mx - nm);
                rmax[r] = nm;
            }
        }
    }
    __syncthreads();
    for (int rr = 0; rr < 16; ++rr) {
        int r = wave * 16 + rr;
        float Mx = rmax[r];
        float iZ = 1.0f / rsum[r];
        const float* arow = attn + abase + (size_t)r * SPAN;
        float* orow = attn_out + abase + (size_t)r * SPAN;
#pragma unroll
        for (int j = 0; j < 16; ++j) {
            float a = arow[j * 64 + lane] * 0.125f;
            orow[j * 64 + lane] = __expf(a - Mx) * iZ;
        }
    }
    float acc2[4][4] = {};
    for (int p0 = 0; p0 < PP; p0 += 64) {
        __syncthreads();
#pragma unroll
        for (int j = 0; j < 16; ++j) {
            int idx = j * 256 + t;
            int d = idx >> 6, pc = idx & 63;
            ks[pc][d] = key[kbase + (size_t)d * PP + p0 + pc];
        }
#pragma unroll
        for (int j = 0; j < 16; ++j) {
            int idx = j * 256 + t;
            int pc = idx >> 6, d = idx & 63;
            vs[pc][d] = val[vbase + (size_t)(p0 + pc) * DD + d];
        }
        __syncthreads();
        float acc[4][4] = {};
#pragma unroll
        for (int d0 = 0; d0 < DD; d0 += 4) {
            float4 q4[4], k4[4];
#pragma unroll
            for (int rr = 0; rr < 4; ++rr) q4[rr] = *(const float4*)&qs[r0 + rr][d0];
#pragma unroll
            for (int cc = 0; cc < 4; ++cc) k4[cc] = *(const float4*)&ks[c0 + cc][d0];
#pragma unroll
            for (int rr = 0; rr < 4; ++rr)
#pragma unroll
                for (int cc = 0; cc < 4; ++cc)
                    acc[rr][cc] += q4[rr].x * k4[cc].x + q4[rr].y * k4[cc].y
                                 + q4[rr].z * k4[cc].z + q4[rr].w * k4[cc].w;
        }
#pragma unroll
        for (int rr = 0; rr < 4; ++rr) {
            float Mx = rmax[r0 + rr];
#pragma unroll
            for (int cc = 0; cc < 4; ++cc)
                sc[r0 + rr][c0 + cc] = __expf(acc[rr][cc] - Mx);
        }
        __syncthreads();
        for (int pc = 0; pc < 64; ++pc) {
            float4 v4 = *(const float4*)&vs[pc][tc * 4];
#pragma unroll
            for (int rr = 0; rr < 4; ++rr) {
                float pr = sc[r0 + rr][pc];
                acc2[rr][0] += pr * v4.x;
                acc2[rr][1] += pr * v4.y;
                acc2[rr][2] += pr * v4.z;
                acc2[rr][3] += pr * v4.w;
            }
        }
    }
#pragma unroll
    for (int rr = 0; rr < 4; ++rr) {
        int r = r0 + rr;
        float s = 32.0f / rsum[r];
        float4 o;
        o.x = acc2[rr][0] * s; o.y = acc2[rr][1] * s;
        o.z = acc2[rr][2] * s; o.w = acc2[rr][3] * s;
        *(float4*)&out[(size_t)bh * MM * DD + (size_t)(m0 + r) * DD + tc * 4] = o;
    }
}

extern "C" void kernel_launch(void* const* d_in, const int* in_sizes, int n_in,
                              void* d_out, int out_size, void* d_ws, size_t ws_size,
                              hipStream_t stream) {
    const float* q    = (const float*)d_in[0];
    const float* attn = (const float*)d_in[1];
    const float* key  = (const float*)d_in[2];
    const float* val  = (const float*)d_in[3];
    float* attn_out = (float*)d_out;
    float* out      = (float*)d_out + (size_t)BH * MM * SPAN;

    if (ws_size >= WS_NEED) {
        ushort_t* wsKV   = (ushort_t*)d_ws;
        float*    ws_MiZ = (float*)((char*)d_ws + WS_MIZ_OFF);
        pm_pre <<<1024, 256, 0, stream>>>(key, val, wsKV);
        pm_main<<<512, 512, 0, stream>>>(q, attn, wsKV, ws_MiZ, out);
        pm_norm<<<8192, 256, 0, stream>>>(attn, ws_MiZ, attn_out);
    } else {
        dim3 grid(MM / 64, BH);
        pm_fallback<<<grid, 256, 0, stream>>>(q, attn, key, val, attn_out, out);
    }
}